// Round 4
// baseline (577.431 us; speedup 1.0000x reference)
//
#include <hip/hip_runtime.h>
#include <math.h>

#define N 1024
#define BATCH 32
#define NT 256
// pad one complex per 16 — ~2-way (free) on q=256/64/4 stages, 4-way on q=16
#define PADC(i) ((i) + ((i) >> 4))

typedef float2 cf;
__device__ __forceinline__ cf cadd(cf a, cf b){ return make_float2(a.x+b.x, a.y+b.y); }
__device__ __forceinline__ cf csub(cf a, cf b){ return make_float2(a.x-b.x, a.y-b.y); }
__device__ __forceinline__ cf cmul(cf a, cf b){ return make_float2(a.x*b.x - a.y*b.y, a.x*b.y + a.y*b.x); }

// base-4 digit reversal (4 digits / 5 digits)
__device__ __forceinline__ int rev8(int q){
    int r = (int)(__brev((unsigned)q) >> 24);
    return ((r & 0x55) << 1) | ((r >> 1) & 0x55);
}
__device__ __forceinline__ int rev10(int m){
    int r = (int)(__brev((unsigned)m) >> 22);
    return ((r & 0x155) << 1) | ((r >> 1) & 0x155);
}

// In-place radix-4 DIF butterfly with register twiddles (no transcendentals).
__device__ __forceinline__ void dif4w(cf* w, int base, int q, cf w1, cf w2, cf w3){
    cf x0 = w[PADC(base)];
    cf x1 = w[PADC(base + q)];
    cf x2 = w[PADC(base + 2*q)];
    cf x3 = w[PADC(base + 3*q)];
    cf A = cadd(x0,x2), Bs = cadd(x1,x3);
    cf C = csub(x0,x2), D = csub(x1,x3);
    cf Dmi = make_float2(D.y, -D.x);
    w[PADC(base)]       = cadd(A,Bs);
    w[PADC(base + q)]   = cmul(cadd(C,Dmi), w1);
    w[PADC(base + 2*q)] = cmul(csub(A,Bs), w2);
    w[PADC(base + 3*q)] = cmul(csub(C,Dmi), w3);
}

// ---- hilbert_k's self-contained stages (32 blocks — sincospif is fine here)
template<int LOG2N>
__device__ __forceinline__ void dif_stage(cf* w, int t){
    const int n = 1 << LOG2N, q = n >> 2;
    int j = t & (q - 1);
    int base = ((t >> (LOG2N - 2)) << LOG2N) + j;
    float sn, cs;
    sincospif((float)j * (2.0f / (float)n), &sn, &cs);
    cf w1 = make_float2(cs, -sn);
    cf w2 = cmul(w1,w1);
    cf w3 = cmul(w2,w1);
    dif4w(w, base, q, w1, w2, w3);
}
template<int LOG2N>
__device__ __forceinline__ void dit_stage(cf* w, int t){
    const int n = 1 << LOG2N, q = n >> 2;
    int j = t & (q - 1);
    int base = ((t >> (LOG2N - 2)) << LOG2N) + j;
    cf x0 = w[PADC(base)];
    cf x1 = w[PADC(base + q)];
    cf x2 = w[PADC(base + 2*q)];
    cf x3 = w[PADC(base + 3*q)];
    float sn, cs;
    sincospif((float)j * (2.0f / (float)n), &sn, &cs);
    cf w1 = make_float2(cs, -sn);
    cf w2 = cmul(w1,w1);
    cf w3 = cmul(w2,w1);
    x1 = cmul(x1,w1); x2 = cmul(x2,w2); x3 = cmul(x3,w3);
    cf A = cadd(x0,x2), Bs = cadd(x1,x3);
    cf C = csub(x0,x2), D = csub(x1,x3);
    cf Dmi = make_float2(D.y, -D.x);
    w[PADC(base)]       = cadd(A,Bs);
    w[PADC(base + q)]   = cadd(C,Dmi);
    w[PADC(base + 2*q)] = csub(A,Bs);
    w[PADC(base + 3*q)] = csub(C,Dmi);
}

// ---------------------------------------------------------------------------
// hilbert_k: analytic signal + fused label MSE (as round 3), plus:
//   - block 0 writes the 1020-entry stage-twiddle table for shg_k
//   - every block writes ca[n] = a[n] * SF[n]  (folds SF into stage-1)
// ---------------------------------------------------------------------------
__global__ __launch_bounds__(NT) void hilbert_k(const float* __restrict__ pred,
                                                const float* __restrict__ label,
                                                cf* __restrict__ a,
                                                cf* __restrict__ ca,
                                                cf* __restrict__ twg,
                                                float* __restrict__ mseJ) {
    __shared__ cf wk[1088];
    __shared__ float rbuf[4][4];
    __shared__ int ibuf[4][4];
    __shared__ int s_first, s_last;
    int t = threadIdx.x, b = blockIdx.x;
    if (b == 0) {
        // twiddle table: entry = W^(m*j*s), W = exp(-2*pi*i/1024)
        for (int i = t; i < 1020; i += NT) {
            int m, j, s;
            if (i < 768)       { m = (i >> 8) + 1; j = i & 255;         s = 1;  }
            else if (i < 960)  { int r = i - 768;  m = (r >> 6) + 1; j = r & 63; s = 4;  }
            else if (i < 1008) { int r = i - 960;  m = (r >> 4) + 1; j = r & 15; s = 16; }
            else               { int r = i - 1008; m = (r >> 2) + 1; j = r & 3;  s = 64; }
            float sn, cs;
            sincospif((float)(m * j * s) * (1.0f / 512.0f), &sn, &cs);
            twg[i] = make_float2(cs, -sn);
        }
    }
    for (int i = t; i < N; i += NT) wk[PADC(i)] = make_float2(pred[b * N + i], 0.f);
    __syncthreads();
    dif_stage<10>(wk, t); __syncthreads();
    dif_stage<8>(wk, t);  __syncthreads();
    dif_stage<6>(wk, t);  __syncthreads();
    dif_stage<4>(wk, t);  __syncthreads();
    dif_stage<2>(wk, t);  __syncthreads();
    for (int i = t; i < N; i += NT) {
        int k = rev10(i);
        float f = (k < 512) ? 0.f : ((k == 512) ? 1.f : 2.f);
        cf v = wk[PADC(i)];
        wk[PADC(i)] = make_float2(f * v.x, -f * v.y);
    }
    __syncthreads();
    dit_stage<2>(wk, t);  __syncthreads();
    dit_stage<4>(wk, t);  __syncthreads();
    dit_stage<6>(wk, t);  __syncthreads();
    dit_stage<8>(wk, t);  __syncthreads();
    dit_stage<10>(wk, t); __syncthreads();
    const float sc = 1.f / (float)N;
    for (int i = t; i < N; i += NT) {
        cf v = wk[PADC(i)];
        cf av = make_float2(v.x * sc, -v.y * sc);
        wk[PADC(i)] = av;
        a[b * N + i] = av;
        float p = (float)(3.525 * (double)(i - 512));
        float s_, c_;
        sincosf(p, &s_, &c_);
        // av * (c, -s)
        ca[b * N + i] = make_float2(av.x * c_ + av.y * s_, av.y * c_ - av.x * s_);
    }
    __syncthreads();

    int w = t >> 6, lane = t & 63;
    int mnR = N, mxR = -1, mnI = N, mxI = -1;
    for (int n = t; n < N; n += NT) {
        float lr = label[b * 2 * N + n];
        float li = label[b * 2 * N + N + n];
        if (fabsf(lr) > 0.01f) { mnR = min(mnR, n); mxR = max(mxR, n); }
        if (fabsf(li) > 0.01f) { mnI = min(mnI, n); mxI = max(mxI, n); }
    }
    for (int o = 32; o > 0; o >>= 1) {
        mnR = min(mnR, __shfl_down(mnR, o));
        mxR = max(mxR, __shfl_down(mxR, o));
        mnI = min(mnI, __shfl_down(mnI, o));
        mxI = max(mxI, __shfl_down(mxI, o));
    }
    if (lane == 0) { ibuf[w][0] = mnR; ibuf[w][1] = mxR; ibuf[w][2] = mnI; ibuf[w][3] = mxI; }
    __syncthreads();
    if (t == 0) {
        int a0 = N, a1 = -1, a2 = N, a3 = -1;
        for (int i = 0; i < 4; ++i) {
            a0 = min(a0, ibuf[i][0]); a1 = max(a1, ibuf[i][1]);
            a2 = min(a2, ibuf[i][2]); a3 = max(a3, ibuf[i][3]);
        }
        int fr   = (a0 == N) ? 0 : a0;
        int lstR = (a1 < 0) ? (N - 1) : a1;
        int fi   = (a2 == N) ? 0 : a2;
        int lstI = (a3 < 0) ? (N - 1) : a3;
        s_first = min(fr, fi);
        s_last  = max(lstR, lstI);
    }
    __syncthreads();
    int first = s_first, last = s_last;

    float m_r = 0.f, m_i = 0.f, m_n = 0.f, m_p = 0.f;
    for (int n = t; n < N; n += NT) {
        cf p = wk[PADC(n)];
        float lr = label[b * 2 * N + n];
        float li = label[b * 2 * N + N + n];
        bool in = (n >= first) && (n < last);
        float pm  = in ? 10.f : 1.f;
        float phm = in ? 1.f : 0.f;
        float dr = p.x - lr, di = p.y - li;
        float dn = (p.x * p.x + p.y * p.y) - (lr * lr + li * li);
        float dp = atan2f(p.y, p.x) - atan2f(li, lr);
        m_r += dr * dr * pm;
        m_i += di * di * pm;
        m_n += dn * dn * pm;
        m_p += dp * dp * phm;
    }
    for (int o = 32; o > 0; o >>= 1) {
        m_r += __shfl_down(m_r, o);
        m_i += __shfl_down(m_i, o);
        m_n += __shfl_down(m_n, o);
        m_p += __shfl_down(m_p, o);
    }
    if (lane == 0) { rbuf[w][0] = m_r; rbuf[w][1] = m_i; rbuf[w][2] = m_n; rbuf[w][3] = m_p; }
    __syncthreads();
    if (t == 0) {
        float s = 0.f;
        for (int i = 0; i < 4; ++i) s += rbuf[i][0] + rbuf[i][1] + rbuf[i][2] + rbuf[i][3];
        mseJ[b] = s * (1.f / (float)N) * 0.25f;
    }
}

// ---------------------------------------------------------------------------
// shg_k: one block per (b,d). Twiddles preloaded from the global table into
// registers (no transcendentals). Stage1 fused with row product (ca read
// coalesced from global, shifted a from LDS); stage5 fused with reduction;
// per-block stats accumulated via device atomics into 5x32 slots.
// ---------------------------------------------------------------------------
__global__ __launch_bounds__(NT) void shg_k(const cf* __restrict__ a,
                                            const cf* __restrict__ cag,
                                            const float* __restrict__ tref,
                                            const cf* __restrict__ twg,
                                            float* __restrict__ Praw,
                                            float* __restrict__ Prt,
                                            unsigned int* __restrict__ Pmaxu,
                                            float* __restrict__ Pt,
                                            float* __restrict__ Ptt) {
    __shared__ cf sha[N];
    __shared__ cf wk[1088];
    __shared__ float rbuf[4][8];
    int t = threadIdx.x, bd = blockIdx.x;
    int b = bd >> 10, d = bd & 1023, delay = d - 512;

    // register twiddles for stages 1-4 (addresses depend only on t -> hoisted)
    cf w1a = twg[t],            w2a = twg[256 + t],        w3a = twg[512 + t];
    int j2 = t & 63;
    cf w1b = twg[768 + j2],     w2b = twg[832 + j2],       w3b = twg[896 + j2];
    int j3 = t & 15;
    cf w1c = twg[960 + j3],     w2c = twg[976 + j3],       w3c = twg[992 + j3];
    int j4 = t & 3;
    cf w1d = twg[1008 + j4],    w2d = twg[1012 + j4],      w3d = twg[1016 + j4];

    for (int i = t; i < N; i += NT) sha[i] = a[b * N + i];
    __syncthreads();

    // ---- stage 1 (n=1024, q=256, base=t, j=t), fftshift folded ----
    {
        const cf* carow = cag + b * N;
        cf x[4];
#pragma unroll
        for (int k = 0; k < 4; ++k) {
            int n_ = (t + 256 * k + 512) & 1023;
            x[k] = cmul(carow[n_], sha[(n_ - delay) & 1023]);
        }
        cf A = cadd(x[0],x[2]), Bs = cadd(x[1],x[3]);
        cf C = csub(x[0],x[2]), D = csub(x[1],x[3]);
        cf Dmi = make_float2(D.y, -D.x);
        wk[PADC(t)]       = cadd(A,Bs);
        wk[PADC(t + 256)] = cmul(cadd(C,Dmi), w1a);
        wk[PADC(t + 512)] = cmul(csub(A,Bs), w2a);
        wk[PADC(t + 768)] = cmul(csub(C,Dmi), w3a);
    }
    __syncthreads();
    dif4w(wk, ((t >> 6) << 8) + j2, 64, w1b, w2b, w3b); __syncthreads();
    dif4w(wk, ((t >> 4) << 6) + j3, 16, w1c, w2c, w3c); __syncthreads();
    dif4w(wk, ((t >> 2) << 4) + j4,  4, w1d, w2d, w3d); __syncthreads();

    // ---- stage 5 (n=4, unit twiddles) fused with reduction ----
    float sraw = 0.f, srt = 0.f, mx = 0.f, st = 0.f, stt = 0.f;
    const float* trow = tref + ((size_t)bd << 10);
    {
        int base = 4 * t;
        cf x0 = wk[PADC(base)], x1 = wk[PADC(base+1)];
        cf x2 = wk[PADC(base+2)], x3 = wk[PADC(base+3)];
        cf A = cadd(x0,x2), Bs = cadd(x1,x3);
        cf C = csub(x0,x2), D = csub(x1,x3);
        cf Dmi = make_float2(D.y, -D.x);
        cf y[4];
        y[0] = cadd(A,Bs); y[1] = cadd(C,Dmi); y[2] = csub(A,Bs); y[3] = csub(C,Dmi);
        int rq = rev8(t);   // stored[4t+m] = F[(m<<8) + rq]
#pragma unroll
        for (int m = 0; m < 4; ++m) {
            float m2 = y[m].x * y[m].x + y[m].y * y[m].y;
            float tv = trow[(((m + 2) & 3) << 8) + rq];  // (bin+512)&1023
            sraw += m2;
            srt += m2 * tv;
            mx = fmaxf(mx, m2);
            st += tv;
            stt += tv * tv;
        }
    }
    for (int o = 32; o > 0; o >>= 1) {
        sraw += __shfl_down(sraw, o);
        srt  += __shfl_down(srt, o);
        mx    = fmaxf(mx, __shfl_down(mx, o));
        st   += __shfl_down(st, o);
        stt  += __shfl_down(stt, o);
    }
    int w = t >> 6, lane = t & 63;
    if (lane == 0) {
        rbuf[w][0] = sraw; rbuf[w][1] = srt; rbuf[w][2] = mx;
        rbuf[w][3] = st;   rbuf[w][4] = stt;
    }
    __syncthreads();
    if (t == 0) {
        float a0 = 0.f, a1 = 0.f, a2 = 0.f, a3 = 0.f, a4 = 0.f;
        for (int i = 0; i < 4; ++i) {
            a0 += rbuf[i][0]; a1 += rbuf[i][1]; a2 = fmaxf(a2, rbuf[i][2]);
            a3 += rbuf[i][3]; a4 += rbuf[i][4];
        }
        atomicAdd(&Praw[b], a0);
        atomicAdd(&Prt[b], a1);
        atomicMax(&Pmaxu[b], __float_as_uint(a2));   // valid: a2 >= 0
        atomicAdd(&Pt[b], a3);
        atomicAdd(&Ptt[b], a4);
    }
}

// ---------------------------------------------------------------------------
// loss1_k: single 64-thread block. Lane b<32: frog + mseJ -> mean -> out[0].
// ---------------------------------------------------------------------------
__global__ __launch_bounds__(64) void loss1_k(const float* __restrict__ Praw,
                                              const float* __restrict__ Prt,
                                              const unsigned int* __restrict__ Pmaxu,
                                              const float* __restrict__ Pt,
                                              const float* __restrict__ Ptt,
                                              const float* __restrict__ mseJ,
                                              float* __restrict__ out) {
    int t = threadIdx.x;
    float val = 0.f;
    if (t < BATCH) {
        float A0 = Praw[t], A1 = Prt[t], A3 = Pt[t], A4 = Ptt[t];
        float A2 = __uint_as_float(Pmaxu[t]);
        float mu = (A1 / A2) / A4;
        float diff = A0 / A2 - mu * A3;
        float frog = fabsf(diff) * (1.f / (float)N);
        val = (mseJ[t] + frog) * (1.f / (float)BATCH);
    }
    for (int o = 32; o > 0; o >>= 1) val += __shfl_down(val, o);
    if (t == 0) out[0] = val;
}

extern "C" void kernel_launch(void* const* d_in, const int* in_sizes, int n_in,
                              void* d_out, int out_size, void* d_ws, size_t ws_size,
                              hipStream_t stream) {
    (void)in_sizes; (void)n_in; (void)out_size; (void)ws_size;
    const float* pred  = (const float*)d_in[0];
    const float* label = (const float*)d_in[1];
    const float* shg   = (const float*)d_in[2];
    float* out = (float*)d_out;

    char* ws = (char*)d_ws;
    cf* a   = (cf*)ws;                                           // B*N cf (256 KB)
    cf* ca  = a + (size_t)BATCH * N;                             // B*N cf (256 KB)
    cf* twg = ca + (size_t)BATCH * N;                            // 1020 cf (~8 KB)
    float* mseJ = (float*)(twg + 1024);                          // B floats
    float* Pacc = mseJ + BATCH;                                  // 5*B floats
    float* Praw = Pacc;
    float* Prt  = Pacc + BATCH;
    unsigned int* Pmaxu = (unsigned int*)(Pacc + 2 * BATCH);
    float* Pt   = Pacc + 3 * BATCH;
    float* Ptt  = Pacc + 4 * BATCH;

    hipMemsetAsync(Pacc, 0, 5 * BATCH * sizeof(float), stream);
    hilbert_k<<<BATCH, NT, 0, stream>>>(pred, label, a, ca, twg, mseJ);
    shg_k<<<BATCH * N, NT, 0, stream>>>(a, ca, shg, twg, Praw, Prt, Pmaxu, Pt, Ptt);
    loss1_k<<<1, 64, 0, stream>>>(Praw, Prt, Pmaxu, Pt, Ptt, mseJ, out);
}

// Round 5
// 266.055 us; speedup vs baseline: 2.1703x; 2.1703x over previous
//
#include <hip/hip_runtime.h>
#include <math.h>

#define N 1024
#define BATCH 32
#define NT 256
// pad one complex per 32 (round-3 measured config)
#define PADC(i) ((i) + ((i) >> 5))

// wave-local LDS ordering: all prior ds_writes of this wave visible to
// subsequent ds_reads; memory clobber stops compiler reordering.
#define WSYNC() asm volatile("s_waitcnt lgkmcnt(0)" ::: "memory")

typedef float2 cf;
__device__ __forceinline__ cf cadd(cf a, cf b){ return make_float2(a.x+b.x, a.y+b.y); }
__device__ __forceinline__ cf csub(cf a, cf b){ return make_float2(a.x-b.x, a.y-b.y); }
__device__ __forceinline__ cf cmul(cf a, cf b){ return make_float2(a.x*b.x - a.y*b.y, a.x*b.y + a.y*b.x); }

// exp(-2*pi*i*jn), jn in revolutions. v_sin_f32/v_cos_f32 take revolutions
// directly (D = sin(S0*2pi)) — no range reduction needed for jn in [0,0.25).
__device__ __forceinline__ cf twiddle(float jn){
    float s = __builtin_amdgcn_sinf(jn);
    float c = __builtin_amdgcn_cosf(jn);
    return make_float2(c, -s);
}

// base-4 digit reversal (4 digits / 5 digits)
__device__ __forceinline__ int rev8(int q){
    int r = (int)(__brev((unsigned)q) >> 24);
    return ((r & 0x55) << 1) | ((r >> 1) & 0x55);
}
__device__ __forceinline__ int rev10(int m){
    int r = (int)(__brev((unsigned)m) >> 22);
    return ((r & 0x155) << 1) | ((r >> 1) & 0x155);
}

// In-place radix-4 DIF butterfly, twiddles computed in-register.
__device__ __forceinline__ void dif4(cf* w, int base, int q, float jn){
    cf x0 = w[PADC(base)];
    cf x1 = w[PADC(base + q)];
    cf x2 = w[PADC(base + 2*q)];
    cf x3 = w[PADC(base + 3*q)];
    cf A = cadd(x0,x2), Bs = cadd(x1,x3);
    cf C = csub(x0,x2), D = csub(x1,x3);
    cf Dmi = make_float2(D.y, -D.x);
    cf w1 = twiddle(jn);
    cf w2 = cmul(w1,w1);
    cf w3 = cmul(w2,w1);
    w[PADC(base)]       = cadd(A,Bs);
    w[PADC(base + q)]   = cmul(cadd(C,Dmi), w1);
    w[PADC(base + 2*q)] = cmul(csub(A,Bs), w2);
    w[PADC(base + 3*q)] = cmul(csub(C,Dmi), w3);
}

template<int LOG2N>
__device__ __forceinline__ void dif_stage(cf* w, int t){
    const int n = 1 << LOG2N, q = n >> 2;
    int j = t & (q - 1);
    int base = ((t >> (LOG2N - 2)) << LOG2N) + j;
    dif4(w, base, q, (float)j * (1.0f / (float)n));
}
template<int LOG2N>
__device__ __forceinline__ void dit_stage(cf* w, int t){
    const int n = 1 << LOG2N, q = n >> 2;
    int j = t & (q - 1);
    int base = ((t >> (LOG2N - 2)) << LOG2N) + j;
    cf x0 = w[PADC(base)];
    cf x1 = w[PADC(base + q)];
    cf x2 = w[PADC(base + 2*q)];
    cf x3 = w[PADC(base + 3*q)];
    cf w1 = twiddle((float)j * (1.0f / (float)n));
    cf w2 = cmul(w1,w1);
    cf w3 = cmul(w2,w1);
    x1 = cmul(x1,w1); x2 = cmul(x2,w2); x3 = cmul(x3,w3);
    cf A = cadd(x0,x2), Bs = cadd(x1,x3);
    cf C = csub(x0,x2), D = csub(x1,x3);
    cf Dmi = make_float2(D.y, -D.x);
    w[PADC(base)]       = cadd(A,Bs);
    w[PADC(base + q)]   = cadd(C,Dmi);
    w[PADC(base + 2*q)] = csub(A,Bs);
    w[PADC(base + 3*q)] = csub(C,Dmi);
}

// ---------------------------------------------------------------------------
// hilbert_k: analytic signal a, ca = a*SF, fused label MSE -> mseJ[b].
// ---------------------------------------------------------------------------
__global__ __launch_bounds__(NT) void hilbert_k(const float* __restrict__ pred,
                                                const float* __restrict__ label,
                                                cf* __restrict__ a,
                                                cf* __restrict__ ca,
                                                float* __restrict__ mseJ) {
    __shared__ cf wk[1056];
    __shared__ float rbuf[4][4];
    __shared__ int ibuf[4][4];
    __shared__ int s_first, s_last;
    int t = threadIdx.x, b = blockIdx.x;
    for (int i = t; i < N; i += NT) wk[PADC(i)] = make_float2(pred[b * N + i], 0.f);
    __syncthreads();
    dif_stage<10>(wk, t); __syncthreads();
    dif_stage<8>(wk, t);  __syncthreads();
    dif_stage<6>(wk, t);  __syncthreads();
    dif_stage<4>(wk, t);  __syncthreads();
    dif_stage<2>(wk, t);  __syncthreads();
    for (int i = t; i < N; i += NT) {
        int k = rev10(i);
        float f = (k < 512) ? 0.f : ((k == 512) ? 1.f : 2.f);
        cf v = wk[PADC(i)];
        wk[PADC(i)] = make_float2(f * v.x, -f * v.y);
    }
    __syncthreads();
    dit_stage<2>(wk, t);  __syncthreads();
    dit_stage<4>(wk, t);  __syncthreads();
    dit_stage<6>(wk, t);  __syncthreads();
    dit_stage<8>(wk, t);  __syncthreads();
    dit_stage<10>(wk, t); __syncthreads();
    const float sc = 1.f / (float)N;
    for (int i = t; i < N; i += NT) {
        cf v = wk[PADC(i)];
        cf av = make_float2(v.x * sc, -v.y * sc);
        wk[PADC(i)] = av;
        a[b * N + i] = av;
        // SF[i] = exp(-i * fl32(3.525*(i-512))); accurate OCML sincosf here
        float p = (float)(3.525 * (double)(i - 512));
        float s_, c_;
        sincosf(p, &s_, &c_);
        ca[b * N + i] = make_float2(av.x * c_ + av.y * s_, av.y * c_ - av.x * s_);
    }
    __syncthreads();

    int w = t >> 6, lane = t & 63;
    int mnR = N, mxR = -1, mnI = N, mxI = -1;
    for (int n = t; n < N; n += NT) {
        float lr = label[b * 2 * N + n];
        float li = label[b * 2 * N + N + n];
        if (fabsf(lr) > 0.01f) { mnR = min(mnR, n); mxR = max(mxR, n); }
        if (fabsf(li) > 0.01f) { mnI = min(mnI, n); mxI = max(mxI, n); }
    }
    for (int o = 32; o > 0; o >>= 1) {
        mnR = min(mnR, __shfl_down(mnR, o));
        mxR = max(mxR, __shfl_down(mxR, o));
        mnI = min(mnI, __shfl_down(mnI, o));
        mxI = max(mxI, __shfl_down(mxI, o));
    }
    if (lane == 0) { ibuf[w][0] = mnR; ibuf[w][1] = mxR; ibuf[w][2] = mnI; ibuf[w][3] = mxI; }
    __syncthreads();
    if (t == 0) {
        int a0 = N, a1 = -1, a2 = N, a3 = -1;
        for (int i = 0; i < 4; ++i) {
            a0 = min(a0, ibuf[i][0]); a1 = max(a1, ibuf[i][1]);
            a2 = min(a2, ibuf[i][2]); a3 = max(a3, ibuf[i][3]);
        }
        int fr   = (a0 == N) ? 0 : a0;
        int lstR = (a1 < 0) ? (N - 1) : a1;
        int fi   = (a2 == N) ? 0 : a2;
        int lstI = (a3 < 0) ? (N - 1) : a3;
        s_first = min(fr, fi);
        s_last  = max(lstR, lstI);
    }
    __syncthreads();
    int first = s_first, last = s_last;

    float m_r = 0.f, m_i = 0.f, m_n = 0.f, m_p = 0.f;
    for (int n = t; n < N; n += NT) {
        cf p = wk[PADC(n)];
        float lr = label[b * 2 * N + n];
        float li = label[b * 2 * N + N + n];
        bool in = (n >= first) && (n < last);
        float pm  = in ? 10.f : 1.f;
        float phm = in ? 1.f : 0.f;
        float dr = p.x - lr, di = p.y - li;
        float dn = (p.x * p.x + p.y * p.y) - (lr * lr + li * li);
        float dp = atan2f(p.y, p.x) - atan2f(li, lr);
        m_r += dr * dr * pm;
        m_i += di * di * pm;
        m_n += dn * dn * pm;
        m_p += dp * dp * phm;
    }
    for (int o = 32; o > 0; o >>= 1) {
        m_r += __shfl_down(m_r, o);
        m_i += __shfl_down(m_i, o);
        m_n += __shfl_down(m_n, o);
        m_p += __shfl_down(m_p, o);
    }
    if (lane == 0) { rbuf[w][0] = m_r; rbuf[w][1] = m_i; rbuf[w][2] = m_n; rbuf[w][3] = m_p; }
    __syncthreads();
    if (t == 0) {
        float s = 0.f;
        for (int i = 0; i < 4; ++i) s += rbuf[i][0] + rbuf[i][1] + rbuf[i][2] + rbuf[i][3];
        mseJ[b] = s * (1.f / (float)N) * 0.25f;
    }
}

// ---------------------------------------------------------------------------
// shg_k: one block per (b,d). Stage-1 operands straight from global (L2-hot
// rows); twiddles via hardware v_sin/v_cos; stages 2-5 wave-local (WSYNC).
// ---------------------------------------------------------------------------
__global__ __launch_bounds__(NT) void shg_k(const cf* __restrict__ a,
                                            const cf* __restrict__ cag,
                                            const float* __restrict__ tref,
                                            float* __restrict__ Praw,
                                            float* __restrict__ Prt,
                                            float* __restrict__ Pmax,
                                            float* __restrict__ Pt,
                                            float* __restrict__ Ptt) {
    __shared__ cf wk[1056];
    __shared__ float rbuf[4][8];
    int t = threadIdx.x, bd = blockIdx.x;
    int b = bd >> 10, d = bd & 1023;

    // ---- stage 1 (n=1024, q=256, base=t, j=t), fftshift folded ----
    {
        const cf* arow  = a   + b * N;
        const cf* carow = cag + b * N;
        cf x[4];
#pragma unroll
        for (int k = 0; k < 4; ++k) {
            int n1 = (t + 256 * k + 512) & 1023;       // fftshifted sample
            int n2 = (t + 256 * k - d) & 1023;         // n1 - delay (mod N)
            x[k] = cmul(carow[n1], arow[n2]);
        }
        cf A = cadd(x[0],x[2]), Bs = cadd(x[1],x[3]);
        cf C = csub(x[0],x[2]), D = csub(x[1],x[3]);
        cf Dmi = make_float2(D.y, -D.x);
        cf w1 = twiddle((float)t * (1.0f / 1024.0f));
        cf w2 = cmul(w1,w1);
        cf w3 = cmul(w2,w1);
        wk[PADC(t)]       = cadd(A,Bs);
        wk[PADC(t + 256)] = cmul(cadd(C,Dmi), w1);
        wk[PADC(t + 512)] = cmul(csub(A,Bs), w2);
        wk[PADC(t + 768)] = cmul(csub(C,Dmi), w3);
    }
    __syncthreads();   // cross-wave exchange
    // stages 2-4: each wave owns a disjoint 256-element range -> wave-local
    dif4(wk, ((t >> 6) << 8) + (t & 63), 64, (float)(t & 63) * (1.0f / 256.0f)); WSYNC();
    dif4(wk, ((t >> 4) << 6) + (t & 15), 16, (float)(t & 15) * (1.0f / 64.0f));  WSYNC();
    dif4(wk, ((t >> 2) << 4) + (t & 3),   4, (float)(t & 3)  * (1.0f / 16.0f));  WSYNC();

    // ---- stage 5 (n=4, unit twiddles) fused with reduction ----
    float sraw = 0.f, srt = 0.f, mx = 0.f, st = 0.f, stt = 0.f;
    const float* trow = tref + ((size_t)bd << 10);
    {
        int base = 4 * t;
        cf x0 = wk[PADC(base)], x1 = wk[PADC(base+1)];
        cf x2 = wk[PADC(base+2)], x3 = wk[PADC(base+3)];
        cf A = cadd(x0,x2), Bs = cadd(x1,x3);
        cf C = csub(x0,x2), D = csub(x1,x3);
        cf Dmi = make_float2(D.y, -D.x);
        cf y[4];
        y[0] = cadd(A,Bs); y[1] = cadd(C,Dmi); y[2] = csub(A,Bs); y[3] = csub(C,Dmi);
        int rq = rev8(t);   // stored[4t+m] = F[(m<<8) + rq]
#pragma unroll
        for (int m = 0; m < 4; ++m) {
            float m2 = y[m].x * y[m].x + y[m].y * y[m].y;
            float tv = trow[(((m + 2) & 3) << 8) + rq];  // (bin+512)&1023
            sraw += m2;
            srt += m2 * tv;
            mx = fmaxf(mx, m2);
            st += tv;
            stt += tv * tv;
        }
    }
    for (int o = 32; o > 0; o >>= 1) {
        sraw += __shfl_down(sraw, o);
        srt  += __shfl_down(srt, o);
        mx    = fmaxf(mx, __shfl_down(mx, o));
        st   += __shfl_down(st, o);
        stt  += __shfl_down(stt, o);
    }
    int w = t >> 6, lane = t & 63;
    if (lane == 0) {
        rbuf[w][0] = sraw; rbuf[w][1] = srt; rbuf[w][2] = mx;
        rbuf[w][3] = st;   rbuf[w][4] = stt;
    }
    __syncthreads();
    if (t == 0) {
        float a0 = 0.f, a1 = 0.f, a2 = 0.f, a3 = 0.f, a4 = 0.f;
        for (int i = 0; i < 4; ++i) {
            a0 += rbuf[i][0]; a1 += rbuf[i][1]; a2 = fmaxf(a2, rbuf[i][2]);
            a3 += rbuf[i][3]; a4 += rbuf[i][4];
        }
        Praw[bd] = a0; Prt[bd] = a1; Pmax[bd] = a2; Pt[bd] = a3; Ptt[bd] = a4;
    }
}

// ---------------------------------------------------------------------------
// loss_k: per batch — frog from row partials + mseJ -> atomic mean.
// ---------------------------------------------------------------------------
__global__ __launch_bounds__(NT) void loss_k(const float* __restrict__ Praw,
                                             const float* __restrict__ Prt,
                                             const float* __restrict__ Pmax,
                                             const float* __restrict__ Pt,
                                             const float* __restrict__ Ptt,
                                             const float* __restrict__ mseJ,
                                             float* __restrict__ out) {
    __shared__ float rbuf[4][8];
    int tid = threadIdx.x, b = blockIdx.x;
    int w = tid >> 6, lane = tid & 63;
    float sr = 0.f, srt = 0.f, mx = 0.f, st = 0.f, stt = 0.f;
    for (int i = tid; i < N; i += NT) {
        int idx = b * N + i;
        sr += Praw[idx]; srt += Prt[idx]; mx = fmaxf(mx, Pmax[idx]);
        st += Pt[idx];   stt += Ptt[idx];
    }
    for (int o = 32; o > 0; o >>= 1) {
        sr  += __shfl_down(sr, o);
        srt += __shfl_down(srt, o);
        mx   = fmaxf(mx, __shfl_down(mx, o));
        st  += __shfl_down(st, o);
        stt += __shfl_down(stt, o);
    }
    if (lane == 0) {
        rbuf[w][0] = sr; rbuf[w][1] = srt; rbuf[w][2] = mx;
        rbuf[w][3] = st; rbuf[w][4] = stt;
    }
    __syncthreads();
    if (tid == 0) {
        float A0 = 0.f, A1 = 0.f, A2 = 0.f, A3 = 0.f, A4 = 0.f;
        for (int i = 0; i < 4; ++i) {
            A0 += rbuf[i][0]; A1 += rbuf[i][1]; A2 = fmaxf(A2, rbuf[i][2]);
            A3 += rbuf[i][3]; A4 += rbuf[i][4];
        }
        float mu = (A1 / A2) / A4;
        float diff = A0 / A2 - mu * A3;
        float frog = fabsf(diff) * (1.f / (float)N);
        atomicAdd(out, (mseJ[b] + frog) * (1.f / (float)BATCH));
    }
}

extern "C" void kernel_launch(void* const* d_in, const int* in_sizes, int n_in,
                              void* d_out, int out_size, void* d_ws, size_t ws_size,
                              hipStream_t stream) {
    (void)in_sizes; (void)n_in; (void)out_size; (void)ws_size;
    const float* pred  = (const float*)d_in[0];
    const float* label = (const float*)d_in[1];
    const float* shg   = (const float*)d_in[2];
    float* out = (float*)d_out;

    char* ws = (char*)d_ws;
    cf* a   = (cf*)ws;                                           // B*N cf (256 KB)
    cf* ca  = a + (size_t)BATCH * N;                             // B*N cf (256 KB)
    float* mseJ = (float*)(ca + (size_t)BATCH * N);              // B floats
    float* P = mseJ + BATCH;                                     // 5*B*N floats
    float* Praw = P;
    float* Prt  = P + (size_t)BATCH * N;
    float* Pmax = P + 2 * (size_t)BATCH * N;
    float* Pt   = P + 3 * (size_t)BATCH * N;
    float* Ptt  = P + 4 * (size_t)BATCH * N;

    hipMemsetAsync(d_out, 0, sizeof(float), stream);
    hilbert_k<<<BATCH, NT, 0, stream>>>(pred, label, a, ca, mseJ);
    shg_k<<<BATCH * N, NT, 0, stream>>>(a, ca, shg, Praw, Prt, Pmax, Pt, Ptt);
    loss_k<<<BATCH, NT, 0, stream>>>(Praw, Prt, Pmax, Pt, Ptt, mseJ, out);
}

// Round 6
// 231.676 us; speedup vs baseline: 2.4924x; 1.1484x over previous
//
#include <hip/hip_runtime.h>
#include <math.h>

#define N 1024
#define BATCH 32
#define NT 256
#define ROWS 4
#define RSTRIDE 1092                      // cf per row: 1024 + 64 pad + 4 (rows staggered 8 banks)
#define P16(i) ((i) + ((i) >> 4))         // shg pad: +1 cf per 16
#define PADC(i) ((i) + ((i) >> 5))        // hilbert pad (round-5 measured config)

// wave-local LDS ordering
#define WSYNC() asm volatile("s_waitcnt lgkmcnt(0)" ::: "memory")

typedef float2 cf;
__device__ __forceinline__ cf cadd(cf a, cf b){ return make_float2(a.x+b.x, a.y+b.y); }
__device__ __forceinline__ cf csub(cf a, cf b){ return make_float2(a.x-b.x, a.y-b.y); }
__device__ __forceinline__ cf cmul(cf a, cf b){ return make_float2(a.x*b.x - a.y*b.y, a.x*b.y + a.y*b.x); }

// exp(-2*pi*i*jn), jn in revolutions (v_sin/v_cos take revolutions; jn<0.25 -> no range reduction)
__device__ __forceinline__ cf twiddle(float jn){
    float s = __builtin_amdgcn_sinf(jn);
    float c = __builtin_amdgcn_cosf(jn);
    return make_float2(c, -s);
}

__device__ __forceinline__ int rev10(int m){
    int r = (int)(__brev((unsigned)m) >> 22);
    return ((r & 0x155) << 1) | ((r >> 1) & 0x155);
}

// radix-4 DIF butterfly core
__device__ __forceinline__ void bfly(cf x0, cf x1, cf x2, cf x3,
                                     cf& y0, cf& y1, cf& y2, cf& y3){
    cf A = cadd(x0,x2), Bs = cadd(x1,x3);
    cf C = csub(x0,x2), D = csub(x1,x3);
    cf Dmi = make_float2(D.y, -D.x);
    y0 = cadd(A,Bs); y1 = cadd(C,Dmi); y2 = csub(A,Bs); y3 = csub(C,Dmi);
}

// in-place LDS butterfly with register twiddles, pad-16 layout
__device__ __forceinline__ void dif4p(cf* w, int base, int q, cf w1, cf w2, cf w3){
    cf x0 = w[P16(base)], x1 = w[P16(base+q)], x2 = w[P16(base+2*q)], x3 = w[P16(base+3*q)];
    cf y0, y1, y2, y3; bfly(x0,x1,x2,x3,y0,y1,y2,y3);
    w[P16(base)]     = y0;
    w[P16(base+q)]   = cmul(y1,w1);
    w[P16(base+2*q)] = cmul(y2,w2);
    w[P16(base+3*q)] = cmul(y3,w3);
}

// ---- hilbert_k helpers (pad-32, round-5 verified) ----
__device__ __forceinline__ void dif4h(cf* w, int base, int q, float jn){
    cf x0 = w[PADC(base)], x1 = w[PADC(base+q)], x2 = w[PADC(base+2*q)], x3 = w[PADC(base+3*q)];
    cf y0, y1, y2, y3; bfly(x0,x1,x2,x3,y0,y1,y2,y3);
    cf w1 = twiddle(jn), w2 = cmul(w1,w1), w3 = cmul(w2,w1);
    w[PADC(base)]     = y0;
    w[PADC(base+q)]   = cmul(y1,w1);
    w[PADC(base+2*q)] = cmul(y2,w2);
    w[PADC(base+3*q)] = cmul(y3,w3);
}
template<int LOG2N>
__device__ __forceinline__ void dif_stage(cf* w, int t){
    const int n = 1 << LOG2N, q = n >> 2;
    int j = t & (q - 1);
    int base = ((t >> (LOG2N - 2)) << LOG2N) + j;
    dif4h(w, base, q, (float)j * (1.0f / (float)n));
}
template<int LOG2N>
__device__ __forceinline__ void dit_stage(cf* w, int t){
    const int n = 1 << LOG2N, q = n >> 2;
    int j = t & (q - 1);
    int base = ((t >> (LOG2N - 2)) << LOG2N) + j;
    cf x0 = w[PADC(base)], x1 = w[PADC(base+q)], x2 = w[PADC(base+2*q)], x3 = w[PADC(base+3*q)];
    cf w1 = twiddle((float)j * (1.0f / (float)n));
    cf w2 = cmul(w1,w1), w3 = cmul(w2,w1);
    x1 = cmul(x1,w1); x2 = cmul(x2,w2); x3 = cmul(x3,w3);
    cf y0, y1, y2, y3; bfly(x0,x1,x2,x3,y0,y1,y2,y3);
    w[PADC(base)] = y0; w[PADC(base+q)] = y1; w[PADC(base+2*q)] = y2; w[PADC(base+3*q)] = y3;
}

// ---------------------------------------------------------------------------
// hilbert_k: analytic signal a, ca = a*SF, fused label MSE -> mseJ[b].
// (round-5 verified; unchanged)
// ---------------------------------------------------------------------------
__global__ __launch_bounds__(NT) void hilbert_k(const float* __restrict__ pred,
                                                const float* __restrict__ label,
                                                cf* __restrict__ a,
                                                cf* __restrict__ ca,
                                                float* __restrict__ mseJ) {
    __shared__ cf wk[1056];
    __shared__ float rbuf[4][4];
    __shared__ int ibuf[4][4];
    __shared__ int s_first, s_last;
    int t = threadIdx.x, b = blockIdx.x;
    for (int i = t; i < N; i += NT) wk[PADC(i)] = make_float2(pred[b * N + i], 0.f);
    __syncthreads();
    dif_stage<10>(wk, t); __syncthreads();
    dif_stage<8>(wk, t);  __syncthreads();
    dif_stage<6>(wk, t);  __syncthreads();
    dif_stage<4>(wk, t);  __syncthreads();
    dif_stage<2>(wk, t);  __syncthreads();
    for (int i = t; i < N; i += NT) {
        int k = rev10(i);
        float f = (k < 512) ? 0.f : ((k == 512) ? 1.f : 2.f);
        cf v = wk[PADC(i)];
        wk[PADC(i)] = make_float2(f * v.x, -f * v.y);
    }
    __syncthreads();
    dit_stage<2>(wk, t);  __syncthreads();
    dit_stage<4>(wk, t);  __syncthreads();
    dit_stage<6>(wk, t);  __syncthreads();
    dit_stage<8>(wk, t);  __syncthreads();
    dit_stage<10>(wk, t); __syncthreads();
    const float sc = 1.f / (float)N;
    for (int i = t; i < N; i += NT) {
        cf v = wk[PADC(i)];
        cf av = make_float2(v.x * sc, -v.y * sc);
        wk[PADC(i)] = av;
        a[b * N + i] = av;
        float p = (float)(3.525 * (double)(i - 512));
        float s_, c_;
        sincosf(p, &s_, &c_);
        ca[b * N + i] = make_float2(av.x * c_ + av.y * s_, av.y * c_ - av.x * s_);
    }
    __syncthreads();

    int w = t >> 6, lane = t & 63;
    int mnR = N, mxR = -1, mnI = N, mxI = -1;
    for (int n = t; n < N; n += NT) {
        float lr = label[b * 2 * N + n];
        float li = label[b * 2 * N + N + n];
        if (fabsf(lr) > 0.01f) { mnR = min(mnR, n); mxR = max(mxR, n); }
        if (fabsf(li) > 0.01f) { mnI = min(mnI, n); mxI = max(mxI, n); }
    }
    for (int o = 32; o > 0; o >>= 1) {
        mnR = min(mnR, __shfl_down(mnR, o));
        mxR = max(mxR, __shfl_down(mxR, o));
        mnI = min(mnI, __shfl_down(mnI, o));
        mxI = max(mxI, __shfl_down(mxI, o));
    }
    if (lane == 0) { ibuf[w][0] = mnR; ibuf[w][1] = mxR; ibuf[w][2] = mnI; ibuf[w][3] = mxI; }
    __syncthreads();
    if (t == 0) {
        int a0 = N, a1 = -1, a2 = N, a3 = -1;
        for (int i = 0; i < 4; ++i) {
            a0 = min(a0, ibuf[i][0]); a1 = max(a1, ibuf[i][1]);
            a2 = min(a2, ibuf[i][2]); a3 = max(a3, ibuf[i][3]);
        }
        int fr   = (a0 == N) ? 0 : a0;
        int lstR = (a1 < 0) ? (N - 1) : a1;
        int fi   = (a2 == N) ? 0 : a2;
        int lstI = (a3 < 0) ? (N - 1) : a3;
        s_first = min(fr, fi);
        s_last  = max(lstR, lstI);
    }
    __syncthreads();
    int first = s_first, last = s_last;

    float m_r = 0.f, m_i = 0.f, m_n = 0.f, m_p = 0.f;
    for (int n = t; n < N; n += NT) {
        cf p = wk[PADC(n)];
        float lr = label[b * 2 * N + n];
        float li = label[b * 2 * N + N + n];
        bool in = (n >= first) && (n < last);
        float pm  = in ? 10.f : 1.f;
        float phm = in ? 1.f : 0.f;
        float dr = p.x - lr, di = p.y - li;
        float dn = (p.x * p.x + p.y * p.y) - (lr * lr + li * li);
        float dp = atan2f(p.y, p.x) - atan2f(li, lr);
        m_r += dr * dr * pm;
        m_i += di * di * pm;
        m_n += dn * dn * pm;
        m_p += dp * dp * phm;
    }
    for (int o = 32; o > 0; o >>= 1) {
        m_r += __shfl_down(m_r, o);
        m_i += __shfl_down(m_i, o);
        m_n += __shfl_down(m_n, o);
        m_p += __shfl_down(m_p, o);
    }
    if (lane == 0) { rbuf[w][0] = m_r; rbuf[w][1] = m_i; rbuf[w][2] = m_n; rbuf[w][3] = m_p; }
    __syncthreads();
    if (t == 0) {
        float s = 0.f;
        for (int i = 0; i < 4; ++i) s += rbuf[i][0] + rbuf[i][1] + rbuf[i][2] + rbuf[i][3];
        mseJ[b] = s * (1.f / (float)N) * 0.25f;
    }
}

// ---------------------------------------------------------------------------
// shg_k: one block = 4 rows (same b, delays dg..dg+3). Stages 1-3 share
// twiddles across rows; stages 4+5 fused as in-register 16-pt DFT with
// constant W16 twiddles; wave-local after stage 2 (WSYNC).
// ---------------------------------------------------------------------------
__global__ __launch_bounds__(NT) void shg_k(const cf* __restrict__ a,
                                            const cf* __restrict__ cag,
                                            const float* __restrict__ tref,
                                            float* __restrict__ Praw,
                                            float* __restrict__ Prt,
                                            float* __restrict__ Pmax,
                                            float* __restrict__ Pt,
                                            float* __restrict__ Ptt) {
    __shared__ cf wk[ROWS * RSTRIDE];
    __shared__ float rbuf[4][ROWS][5];
    int t = threadIdx.x, blk = blockIdx.x;
    int b = blk >> 8;
    int dg = (blk & 255) << 2;            // delay-indices dg..dg+3 (delay = d-512)
    const cf* arow  = a   + b * N;
    const cf* carow = cag + b * N;

    // ---- stage 1 (q=256): twiddles + ca loads shared across rows ----
    {
        cf w1 = twiddle((float)t * (1.0f / 1024.0f));
        cf w2 = cmul(w1,w1), w3 = cmul(w2,w1);
        cf cav[4];
#pragma unroll
        for (int k = 0; k < 4; ++k) cav[k] = carow[(t + 256*k + 512) & 1023];
#pragma unroll
        for (int r = 0; r < ROWS; ++r) {
            int d = dg + r;
            cf x[4];
#pragma unroll
            for (int k = 0; k < 4; ++k)
                x[k] = cmul(cav[k], arow[(t + 256*k - d) & 1023]);
            cf y0, y1, y2, y3; bfly(x[0],x[1],x[2],x[3],y0,y1,y2,y3);
            cf* w = wk + r * RSTRIDE;
            w[P16(t)]     = y0;
            w[P16(t+256)] = cmul(y1,w1);
            w[P16(t+512)] = cmul(y2,w2);
            w[P16(t+768)] = cmul(y3,w3);
        }
    }
    __syncthreads();
    // ---- stage 2 (q=64): wave w covers [256w..256w+255] of each row ----
    {
        int j = t & 63;
        int base = ((t >> 6) << 8) + j;
        cf w1 = twiddle((float)j * (1.0f / 256.0f));
        cf w2 = cmul(w1,w1), w3 = cmul(w2,w1);
#pragma unroll
        for (int r = 0; r < ROWS; ++r) dif4p(wk + r * RSTRIDE, base, 64, w1, w2, w3);
    }
    WSYNC();
    // ---- stage 3 (q=16) ----
    {
        int j = t & 15;
        int base = ((t >> 4) << 6) + j;
        cf w1 = twiddle((float)j * (1.0f / 64.0f));
        cf w2 = cmul(w1,w1), w3 = cmul(w2,w1);
#pragma unroll
        for (int r = 0; r < ROWS; ++r) dif4p(wk + r * RSTRIDE, base, 16, w1, w2, w3);
    }
    WSYNC();

    // ---- fused stages 4+5: in-register 16-pt DFT, constant twiddles ----
    float sraw = 0.f, srt = 0.f, mx = 0.f, st = 0.f, stt = 0.f;
    {
        const cf W1 = { 0.923879533f, -0.382683432f};
        const cf W2 = { 0.707106781f, -0.707106781f};
        const cf W3 = { 0.382683432f, -0.923879533f};
        const cf W6 = {-0.707106781f, -0.707106781f};
        const cf W9 = {-0.923879533f,  0.382683432f};
        int r = t & 3;
        int g = ((t >> 6) << 4) + ((t >> 2) & 15);   // wave-local group
        cf* w = wk + r * RSTRIDE;
        cf v[16];
        int base = 17 * g;                            // P16(16g+k) = 17g+k, k<16
#pragma unroll
        for (int k = 0; k < 16; ++k) v[k] = w[base + k];
        cf o[16];
        // stage A (q=4): j = 0..3, twiddles W16^{j}, W16^{2j}, W16^{3j}
        bfly(v[0], v[4], v[8], v[12], o[0], o[4], o[8],  o[12]);
        { cf y0,y1,y2,y3; bfly(v[1],v[5],v[9], v[13],y0,y1,y2,y3);
          o[1]=y0; o[5]=cmul(y1,W1); o[9]=cmul(y2,W2); o[13]=cmul(y3,W3); }
        { cf y0,y1,y2,y3; bfly(v[2],v[6],v[10],v[14],y0,y1,y2,y3);
          o[2]=y0; o[6]=cmul(y1,W2); o[10]=make_float2(y2.y,-y2.x); o[14]=cmul(y3,W6); }
        { cf y0,y1,y2,y3; bfly(v[3],v[7],v[11],v[15],y0,y1,y2,y3);
          o[3]=y0; o[7]=cmul(y1,W3); o[11]=cmul(y2,W6); o[15]=cmul(y3,W9); }
        // stage B (q=1, unit twiddles) + pairing with tref
        int bd = b * N + dg + r;
        const float* trow = tref + ((size_t)bd << 10);
        int kb = ((g & 3) << 4) | (g & 12) | (g >> 4);   // base-4 digit reversal of g
#pragma unroll
        for (int u = 0; u < 4; ++u) {
            cf y0, y1, y2, y3;
            bfly(o[4*u], o[4*u+1], o[4*u+2], o[4*u+3], y0, y1, y2, y3);
            cf ys[4] = {y0, y1, y2, y3};
#pragma unroll
            for (int m = 0; m < 4; ++m) {
                float m2 = ys[m].x * ys[m].x + ys[m].y * ys[m].y;
                // stored idx 16g+4u+m holds F[(m<<8)|(u<<6)|kb]; pair with (k+512)&1023
                float tv = trow[(((m + 2) & 3) << 8) | (u << 6) | kb];
                sraw += m2;
                srt += m2 * tv;
                mx = fmaxf(mx, m2);
                st += tv;
                stt += tv * tv;
            }
        }
    }
    // wave reduction over stride-4 lanes (residue = row)
    for (int o = 32; o >= 4; o >>= 1) {
        sraw += __shfl_down(sraw, o);
        srt  += __shfl_down(srt, o);
        mx    = fmaxf(mx, __shfl_down(mx, o));
        st   += __shfl_down(st, o);
        stt  += __shfl_down(stt, o);
    }
    {
        int lane = t & 63, wv = t >> 6;
        if (lane < 4) {
            rbuf[wv][lane][0] = sraw; rbuf[wv][lane][1] = srt; rbuf[wv][lane][2] = mx;
            rbuf[wv][lane][3] = st;   rbuf[wv][lane][4] = stt;
        }
    }
    __syncthreads();
    if (t < ROWS) {
        float a0 = 0.f, a1 = 0.f, a2 = 0.f, a3 = 0.f, a4 = 0.f;
        for (int i = 0; i < 4; ++i) {
            a0 += rbuf[i][t][0]; a1 += rbuf[i][t][1]; a2 = fmaxf(a2, rbuf[i][t][2]);
            a3 += rbuf[i][t][3]; a4 += rbuf[i][t][4];
        }
        int bd = b * N + dg + t;
        Praw[bd] = a0; Prt[bd] = a1; Pmax[bd] = a2; Pt[bd] = a3; Ptt[bd] = a4;
    }
}

// ---------------------------------------------------------------------------
// loss_k: per batch — frog from row partials + mseJ -> atomic mean.
// ---------------------------------------------------------------------------
__global__ __launch_bounds__(NT) void loss_k(const float* __restrict__ Praw,
                                             const float* __restrict__ Prt,
                                             const float* __restrict__ Pmax,
                                             const float* __restrict__ Pt,
                                             const float* __restrict__ Ptt,
                                             const float* __restrict__ mseJ,
                                             float* __restrict__ out) {
    __shared__ float rbuf[4][8];
    int tid = threadIdx.x, b = blockIdx.x;
    int w = tid >> 6, lane = tid & 63;
    float sr = 0.f, srt = 0.f, mx = 0.f, st = 0.f, stt = 0.f;
    for (int i = tid; i < N; i += NT) {
        int idx = b * N + i;
        sr += Praw[idx]; srt += Prt[idx]; mx = fmaxf(mx, Pmax[idx]);
        st += Pt[idx];   stt += Ptt[idx];
    }
    for (int o = 32; o > 0; o >>= 1) {
        sr  += __shfl_down(sr, o);
        srt += __shfl_down(srt, o);
        mx   = fmaxf(mx, __shfl_down(mx, o));
        st  += __shfl_down(st, o);
        stt += __shfl_down(stt, o);
    }
    if (lane == 0) {
        rbuf[w][0] = sr; rbuf[w][1] = srt; rbuf[w][2] = mx;
        rbuf[w][3] = st; rbuf[w][4] = stt;
    }
    __syncthreads();
    if (tid == 0) {
        float A0 = 0.f, A1 = 0.f, A2 = 0.f, A3 = 0.f, A4 = 0.f;
        for (int i = 0; i < 4; ++i) {
            A0 += rbuf[i][0]; A1 += rbuf[i][1]; A2 = fmaxf(A2, rbuf[i][2]);
            A3 += rbuf[i][3]; A4 += rbuf[i][4];
        }
        float mu = (A1 / A2) / A4;
        float diff = A0 / A2 - mu * A3;
        float frog = fabsf(diff) * (1.f / (float)N);
        atomicAdd(out, (mseJ[b] + frog) * (1.f / (float)BATCH));
    }
}

extern "C" void kernel_launch(void* const* d_in, const int* in_sizes, int n_in,
                              void* d_out, int out_size, void* d_ws, size_t ws_size,
                              hipStream_t stream) {
    (void)in_sizes; (void)n_in; (void)out_size; (void)ws_size;
    const float* pred  = (const float*)d_in[0];
    const float* label = (const float*)d_in[1];
    const float* shg   = (const float*)d_in[2];
    float* out = (float*)d_out;

    char* ws = (char*)d_ws;
    cf* a   = (cf*)ws;
    cf* ca  = a + (size_t)BATCH * N;
    float* mseJ = (float*)(ca + (size_t)BATCH * N);
    float* P = mseJ + BATCH;
    float* Praw = P;
    float* Prt  = P + (size_t)BATCH * N;
    float* Pmax = P + 2 * (size_t)BATCH * N;
    float* Pt   = P + 3 * (size_t)BATCH * N;
    float* Ptt  = P + 4 * (size_t)BATCH * N;

    hipMemsetAsync(d_out, 0, sizeof(float), stream);
    hilbert_k<<<BATCH, NT, 0, stream>>>(pred, label, a, ca, mseJ);
    shg_k<<<BATCH * 256, NT, 0, stream>>>(a, ca, shg, Praw, Prt, Pmax, Pt, Ptt);
    loss_k<<<BATCH, NT, 0, stream>>>(Praw, Prt, Pmax, Pt, Ptt, mseJ, out);
}

// Round 7
// 227.689 us; speedup vs baseline: 2.5361x; 1.0175x over previous
//
#include <hip/hip_runtime.h>
#include <math.h>

#define N 1024
#define BATCH 32
#define NT 512
#define ROWS 4
#define RSTRIDE 1092                      // cf per row: 1024 + 64 pad + 4 stagger
#define P16(i) ((i) + ((i) >> 4))         // shg pad: +1 cf per 16
#define PADC(i) ((i) + ((i) >> 5))        // hilbert pad (round-5 measured config)

// wave-local LDS ordering
#define WSYNC() asm volatile("s_waitcnt lgkmcnt(0)" ::: "memory")

typedef float2 cf;
__device__ __forceinline__ cf cadd(cf a, cf b){ return make_float2(a.x+b.x, a.y+b.y); }
__device__ __forceinline__ cf csub(cf a, cf b){ return make_float2(a.x-b.x, a.y-b.y); }
__device__ __forceinline__ cf cmul(cf a, cf b){ return make_float2(a.x*b.x - a.y*b.y, a.x*b.y + a.y*b.x); }

// exp(-2*pi*i*jn), jn in revolutions (v_sin/v_cos take revolutions)
__device__ __forceinline__ cf twiddle(float jn){
    float s = __builtin_amdgcn_sinf(jn);
    float c = __builtin_amdgcn_cosf(jn);
    return make_float2(c, -s);
}

__device__ __forceinline__ int rev10(int m){
    int r = (int)(__brev((unsigned)m) >> 22);
    return ((r & 0x155) << 1) | ((r >> 1) & 0x155);
}

// radix-4 DIF butterfly core
__device__ __forceinline__ void bfly(cf x0, cf x1, cf x2, cf x3,
                                     cf& y0, cf& y1, cf& y2, cf& y3){
    cf A = cadd(x0,x2), Bs = cadd(x1,x3);
    cf C = csub(x0,x2), D = csub(x1,x3);
    cf Dmi = make_float2(D.y, -D.x);
    y0 = cadd(A,Bs); y1 = cadd(C,Dmi); y2 = csub(A,Bs); y3 = csub(C,Dmi);
}

// in-place LDS butterfly with register twiddles, pad-16 layout
__device__ __forceinline__ void dif4p(cf* w, int base, int q, cf w1, cf w2, cf w3){
    cf x0 = w[P16(base)], x1 = w[P16(base+q)], x2 = w[P16(base+2*q)], x3 = w[P16(base+3*q)];
    cf y0, y1, y2, y3; bfly(x0,x1,x2,x3,y0,y1,y2,y3);
    w[P16(base)]     = y0;
    w[P16(base+q)]   = cmul(y1,w1);
    w[P16(base+2*q)] = cmul(y2,w2);
    w[P16(base+3*q)] = cmul(y3,w3);
}

// ---- hilbert_k helpers (pad-32, round-5 verified) ----
__device__ __forceinline__ void dif4h(cf* w, int base, int q, float jn){
    cf x0 = w[PADC(base)], x1 = w[PADC(base+q)], x2 = w[PADC(base+2*q)], x3 = w[PADC(base+3*q)];
    cf y0, y1, y2, y3; bfly(x0,x1,x2,x3,y0,y1,y2,y3);
    cf w1 = twiddle(jn), w2 = cmul(w1,w1), w3 = cmul(w2,w1);
    w[PADC(base)]     = y0;
    w[PADC(base+q)]   = cmul(y1,w1);
    w[PADC(base+2*q)] = cmul(y2,w2);
    w[PADC(base+3*q)] = cmul(y3,w3);
}
template<int LOG2N>
__device__ __forceinline__ void dif_stage(cf* w, int t){
    const int n = 1 << LOG2N, q = n >> 2;
    int j = t & (q - 1);
    int base = ((t >> (LOG2N - 2)) << LOG2N) + j;
    dif4h(w, base, q, (float)j * (1.0f / (float)n));
}
template<int LOG2N>
__device__ __forceinline__ void dit_stage(cf* w, int t){
    const int n = 1 << LOG2N, q = n >> 2;
    int j = t & (q - 1);
    int base = ((t >> (LOG2N - 2)) << LOG2N) + j;
    cf x0 = w[PADC(base)], x1 = w[PADC(base+q)], x2 = w[PADC(base+2*q)], x3 = w[PADC(base+3*q)];
    cf w1 = twiddle((float)j * (1.0f / (float)n));
    cf w2 = cmul(w1,w1), w3 = cmul(w2,w1);
    x1 = cmul(x1,w1); x2 = cmul(x2,w2); x3 = cmul(x3,w3);
    cf y0, y1, y2, y3; bfly(x0,x1,x2,x3,y0,y1,y2,y3);
    w[PADC(base)] = y0; w[PADC(base+q)] = y1; w[PADC(base+2*q)] = y2; w[PADC(base+3*q)] = y3;
}

// ---------------------------------------------------------------------------
// hilbert_k: analytic signal a, ca = a*SF, fused label MSE -> mseJ[b].
// (round-5 verified; unchanged)
// ---------------------------------------------------------------------------
__global__ __launch_bounds__(256) void hilbert_k(const float* __restrict__ pred,
                                                 const float* __restrict__ label,
                                                 cf* __restrict__ a,
                                                 cf* __restrict__ ca,
                                                 float* __restrict__ mseJ) {
    __shared__ cf wk[1056];
    __shared__ float rbuf[4][4];
    __shared__ int ibuf[4][4];
    __shared__ int s_first, s_last;
    int t = threadIdx.x, b = blockIdx.x;
    for (int i = t; i < N; i += 256) wk[PADC(i)] = make_float2(pred[b * N + i], 0.f);
    __syncthreads();
    dif_stage<10>(wk, t); __syncthreads();
    dif_stage<8>(wk, t);  __syncthreads();
    dif_stage<6>(wk, t);  __syncthreads();
    dif_stage<4>(wk, t);  __syncthreads();
    dif_stage<2>(wk, t);  __syncthreads();
    for (int i = t; i < N; i += 256) {
        int k = rev10(i);
        float f = (k < 512) ? 0.f : ((k == 512) ? 1.f : 2.f);
        cf v = wk[PADC(i)];
        wk[PADC(i)] = make_float2(f * v.x, -f * v.y);
    }
    __syncthreads();
    dit_stage<2>(wk, t);  __syncthreads();
    dit_stage<4>(wk, t);  __syncthreads();
    dit_stage<6>(wk, t);  __syncthreads();
    dit_stage<8>(wk, t);  __syncthreads();
    dit_stage<10>(wk, t); __syncthreads();
    const float sc = 1.f / (float)N;
    for (int i = t; i < N; i += 256) {
        cf v = wk[PADC(i)];
        cf av = make_float2(v.x * sc, -v.y * sc);
        wk[PADC(i)] = av;
        a[b * N + i] = av;
        float p = (float)(3.525 * (double)(i - 512));
        float s_, c_;
        sincosf(p, &s_, &c_);
        ca[b * N + i] = make_float2(av.x * c_ + av.y * s_, av.y * c_ - av.x * s_);
    }
    __syncthreads();

    int w = t >> 6, lane = t & 63;
    int mnR = N, mxR = -1, mnI = N, mxI = -1;
    for (int n = t; n < N; n += 256) {
        float lr = label[b * 2 * N + n];
        float li = label[b * 2 * N + N + n];
        if (fabsf(lr) > 0.01f) { mnR = min(mnR, n); mxR = max(mxR, n); }
        if (fabsf(li) > 0.01f) { mnI = min(mnI, n); mxI = max(mxI, n); }
    }
    for (int o = 32; o > 0; o >>= 1) {
        mnR = min(mnR, __shfl_down(mnR, o));
        mxR = max(mxR, __shfl_down(mxR, o));
        mnI = min(mnI, __shfl_down(mnI, o));
        mxI = max(mxI, __shfl_down(mxI, o));
    }
    if (lane == 0) { ibuf[w][0] = mnR; ibuf[w][1] = mxR; ibuf[w][2] = mnI; ibuf[w][3] = mxI; }
    __syncthreads();
    if (t == 0) {
        int a0 = N, a1 = -1, a2 = N, a3 = -1;
        for (int i = 0; i < 4; ++i) {
            a0 = min(a0, ibuf[i][0]); a1 = max(a1, ibuf[i][1]);
            a2 = min(a2, ibuf[i][2]); a3 = max(a3, ibuf[i][3]);
        }
        int fr   = (a0 == N) ? 0 : a0;
        int lstR = (a1 < 0) ? (N - 1) : a1;
        int fi   = (a2 == N) ? 0 : a2;
        int lstI = (a3 < 0) ? (N - 1) : a3;
        s_first = min(fr, fi);
        s_last  = max(lstR, lstI);
    }
    __syncthreads();
    int first = s_first, last = s_last;

    float m_r = 0.f, m_i = 0.f, m_n = 0.f, m_p = 0.f;
    for (int n = t; n < N; n += 256) {
        cf p = wk[PADC(n)];
        float lr = label[b * 2 * N + n];
        float li = label[b * 2 * N + N + n];
        bool in = (n >= first) && (n < last);
        float pm  = in ? 10.f : 1.f;
        float phm = in ? 1.f : 0.f;
        float dr = p.x - lr, di = p.y - li;
        float dn = (p.x * p.x + p.y * p.y) - (lr * lr + li * li);
        float dp = atan2f(p.y, p.x) - atan2f(li, lr);
        m_r += dr * dr * pm;
        m_i += di * di * pm;
        m_n += dn * dn * pm;
        m_p += dp * dp * phm;
    }
    for (int o = 32; o > 0; o >>= 1) {
        m_r += __shfl_down(m_r, o);
        m_i += __shfl_down(m_i, o);
        m_n += __shfl_down(m_n, o);
        m_p += __shfl_down(m_p, o);
    }
    if (lane == 0) { rbuf[w][0] = m_r; rbuf[w][1] = m_i; rbuf[w][2] = m_n; rbuf[w][3] = m_p; }
    __syncthreads();
    if (t == 0) {
        float s = 0.f;
        for (int i = 0; i < 4; ++i) s += rbuf[i][0] + rbuf[i][1] + rbuf[i][2] + rbuf[i][3];
        mseJ[b] = s * (1.f / (float)N) * 0.25f;
    }
}

// ---------------------------------------------------------------------------
// shg_k: one block = 4 rows (same b, delays dg..dg+3), 512 threads (8 waves,
// 4 blocks/CU = 32 waves/CU). Stages 1-3: butterfly id bt = t&255, 2 rows per
// thread (rg = t>>8), twiddles shared across the 2 rows. Fused 16-pt stage:
// threads t<256, wave w owns the whole of row w -> plain 64-lane shuffle
// reduce, lane 0 writes partials (no LDS rbuf, no final barrier).
// ---------------------------------------------------------------------------
__global__ __launch_bounds__(NT, 8) void shg_k(const cf* __restrict__ a,
                                               const cf* __restrict__ cag,
                                               const float* __restrict__ tref,
                                               float* __restrict__ Praw,
                                               float* __restrict__ Prt,
                                               float* __restrict__ Pmax,
                                               float* __restrict__ Pt,
                                               float* __restrict__ Ptt) {
    __shared__ cf wk[ROWS * RSTRIDE];
    int t = threadIdx.x, blk = blockIdx.x;
    int b = blk >> 8;
    int dg = (blk & 255) << 2;            // delay-indices dg..dg+3
    const cf* arow  = a   + b * N;
    const cf* carow = cag + b * N;
    int bt = t & 255, rg = t >> 8;        // butterfly id, row-pair (0:rows 0-1, 1:rows 2-3)

    // ---- stage 1 (q=256): twiddles + ca loads shared across 2 rows ----
    {
        cf w1 = twiddle((float)bt * (1.0f / 1024.0f));
        cf w2 = cmul(w1,w1), w3 = cmul(w2,w1);
        cf cav[4];
#pragma unroll
        for (int k = 0; k < 4; ++k) cav[k] = carow[(bt + 256*k + 512) & 1023];
#pragma unroll
        for (int rr = 0; rr < 2; ++rr) {
            int r = rg * 2 + rr;
            int d = dg + r;
            cf x[4];
#pragma unroll
            for (int k = 0; k < 4; ++k)
                x[k] = cmul(cav[k], arow[(bt + 256*k - d) & 1023]);
            cf y0, y1, y2, y3; bfly(x[0],x[1],x[2],x[3],y0,y1,y2,y3);
            cf* w = wk + r * RSTRIDE;
            w[P16(bt)]     = y0;
            w[P16(bt+256)] = cmul(y1,w1);
            w[P16(bt+512)] = cmul(y2,w2);
            w[P16(bt+768)] = cmul(y3,w3);
        }
    }
    __syncthreads();
    // ---- stage 2 (q=64): wave-local per row-half ----
    {
        int j = bt & 63;
        int base = ((bt >> 6) << 8) + j;
        cf w1 = twiddle((float)j * (1.0f / 256.0f));
        cf w2 = cmul(w1,w1), w3 = cmul(w2,w1);
#pragma unroll
        for (int rr = 0; rr < 2; ++rr) dif4p(wk + (rg*2+rr) * RSTRIDE, base, 64, w1, w2, w3);
    }
    WSYNC();
    // ---- stage 3 (q=16): still wave-local per row-half ----
    {
        int j = bt & 15;
        int base = ((bt >> 4) << 6) + j;
        cf w1 = twiddle((float)j * (1.0f / 64.0f));
        cf w2 = cmul(w1,w1), w3 = cmul(w2,w1);
#pragma unroll
        for (int rr = 0; rr < 2; ++rr) dif4p(wk + (rg*2+rr) * RSTRIDE, base, 16, w1, w2, w3);
    }
    __syncthreads();   // redistribution: fused stage crosses row-halves

    // ---- fused stages 4+5: in-register 16-pt DFT; wave w (w<4) = row w ----
    if (t < 256) {
        const cf W1 = { 0.923879533f, -0.382683432f};
        const cf W2 = { 0.707106781f, -0.707106781f};
        const cf W3 = { 0.382683432f, -0.923879533f};
        const cf W6 = {-0.707106781f, -0.707106781f};
        const cf W9 = {-0.923879533f,  0.382683432f};
        int r = t >> 6;                  // row = wave index
        int g = t & 63;                  // 16-block within row
        cf* w = wk + r * RSTRIDE;
        cf v[16];
        int base = 17 * g;               // P16(16g+k) = 17g+k, k<16
#pragma unroll
        for (int k = 0; k < 16; ++k) v[k] = w[base + k];
        cf o[16];
        bfly(v[0], v[4], v[8], v[12], o[0], o[4], o[8],  o[12]);
        { cf y0,y1,y2,y3; bfly(v[1],v[5],v[9], v[13],y0,y1,y2,y3);
          o[1]=y0; o[5]=cmul(y1,W1); o[9]=cmul(y2,W2); o[13]=cmul(y3,W3); }
        { cf y0,y1,y2,y3; bfly(v[2],v[6],v[10],v[14],y0,y1,y2,y3);
          o[2]=y0; o[6]=cmul(y1,W2); o[10]=make_float2(y2.y,-y2.x); o[14]=cmul(y3,W6); }
        { cf y0,y1,y2,y3; bfly(v[3],v[7],v[11],v[15],y0,y1,y2,y3);
          o[3]=y0; o[7]=cmul(y1,W3); o[11]=cmul(y2,W6); o[15]=cmul(y3,W9); }

        float sraw = 0.f, srt = 0.f, mx = 0.f, st = 0.f, stt = 0.f;
        int bd = b * N + dg + r;
        const float* trow = tref + ((size_t)bd << 10);
        int kb = ((g & 3) << 4) | (g & 12) | (g >> 4);   // base-4 digit reversal of g
#pragma unroll
        for (int u = 0; u < 4; ++u) {
            cf y0, y1, y2, y3;
            bfly(o[4*u], o[4*u+1], o[4*u+2], o[4*u+3], y0, y1, y2, y3);
            cf ys[4] = {y0, y1, y2, y3};
#pragma unroll
            for (int m = 0; m < 4; ++m) {
                float m2 = ys[m].x * ys[m].x + ys[m].y * ys[m].y;
                float tv = trow[(((m + 2) & 3) << 8) | (u << 6) | kb];
                sraw += m2;
                srt += m2 * tv;
                mx = fmaxf(mx, m2);
                st += tv;
                stt += tv * tv;
            }
        }
        // full-wave reduction: wave r covers g = 0..63 = entire row r
        for (int o_ = 32; o_ > 0; o_ >>= 1) {
            sraw += __shfl_down(sraw, o_);
            srt  += __shfl_down(srt, o_);
            mx    = fmaxf(mx, __shfl_down(mx, o_));
            st   += __shfl_down(st, o_);
            stt  += __shfl_down(stt, o_);
        }
        if ((t & 63) == 0) {
            Praw[bd] = sraw; Prt[bd] = srt; Pmax[bd] = mx; Pt[bd] = st; Ptt[bd] = stt;
        }
    }
}

// ---------------------------------------------------------------------------
// loss_k: per batch — frog from row partials + mseJ -> atomic mean.
// ---------------------------------------------------------------------------
__global__ __launch_bounds__(256) void loss_k(const float* __restrict__ Praw,
                                              const float* __restrict__ Prt,
                                              const float* __restrict__ Pmax,
                                              const float* __restrict__ Pt,
                                              const float* __restrict__ Ptt,
                                              const float* __restrict__ mseJ,
                                              float* __restrict__ out) {
    __shared__ float rbuf[4][8];
    int tid = threadIdx.x, b = blockIdx.x;
    int w = tid >> 6, lane = tid & 63;
    float sr = 0.f, srt = 0.f, mx = 0.f, st = 0.f, stt = 0.f;
    for (int i = tid; i < N; i += 256) {
        int idx = b * N + i;
        sr += Praw[idx]; srt += Prt[idx]; mx = fmaxf(mx, Pmax[idx]);
        st += Pt[idx];   stt += Ptt[idx];
    }
    for (int o = 32; o > 0; o >>= 1) {
        sr  += __shfl_down(sr, o);
        srt += __shfl_down(srt, o);
        mx   = fmaxf(mx, __shfl_down(mx, o));
        st  += __shfl_down(st, o);
        stt += __shfl_down(stt, o);
    }
    if (lane == 0) {
        rbuf[w][0] = sr; rbuf[w][1] = srt; rbuf[w][2] = mx;
        rbuf[w][3] = st; rbuf[w][4] = stt;
    }
    __syncthreads();
    if (tid == 0) {
        float A0 = 0.f, A1 = 0.f, A2 = 0.f, A3 = 0.f, A4 = 0.f;
        for (int i = 0; i < 4; ++i) {
            A0 += rbuf[i][0]; A1 += rbuf[i][1]; A2 = fmaxf(A2, rbuf[i][2]);
            A3 += rbuf[i][3]; A4 += rbuf[i][4];
        }
        float mu = (A1 / A2) / A4;
        float diff = A0 / A2 - mu * A3;
        float frog = fabsf(diff) * (1.f / (float)N);
        atomicAdd(out, (mseJ[b] + frog) * (1.f / (float)BATCH));
    }
}

extern "C" void kernel_launch(void* const* d_in, const int* in_sizes, int n_in,
                              void* d_out, int out_size, void* d_ws, size_t ws_size,
                              hipStream_t stream) {
    (void)in_sizes; (void)n_in; (void)out_size; (void)ws_size;
    const float* pred  = (const float*)d_in[0];
    const float* label = (const float*)d_in[1];
    const float* shg   = (const float*)d_in[2];
    float* out = (float*)d_out;

    char* ws = (char*)d_ws;
    cf* a   = (cf*)ws;
    cf* ca  = a + (size_t)BATCH * N;
    float* mseJ = (float*)(ca + (size_t)BATCH * N);
    float* P = mseJ + BATCH;
    float* Praw = P;
    float* Prt  = P + (size_t)BATCH * N;
    float* Pmax = P + 2 * (size_t)BATCH * N;
    float* Pt   = P + 3 * (size_t)BATCH * N;
    float* Ptt  = P + 4 * (size_t)BATCH * N;

    hipMemsetAsync(d_out, 0, sizeof(float), stream);
    hilbert_k<<<BATCH, 256, 0, stream>>>(pred, label, a, ca, mseJ);
    shg_k<<<BATCH * 256, NT, 0, stream>>>(a, ca, shg, Praw, Prt, Pmax, Pt, Ptt);
    loss_k<<<BATCH, 256, 0, stream>>>(Praw, Prt, Pmax, Pt, Ptt, mseJ, out);
}